// Round 7
// baseline (8314.542 us; speedup 1.0000x reference)
//
#include <hip/hip_runtime.h>
#include <hip/hip_bf16.h>
#include <math.h>

#define NN 30000
#define NE 200000
#define NT 3
#define NR 5
#define NH 8
#define DIM 256
#define ML 240
#define EPSF 1e-5f

typedef __attribute__((ext_vector_type(8))) short short8v;
typedef __attribute__((ext_vector_type(4))) float f32x4;

__device__ __forceinline__ unsigned short f2bf(float f){
    unsigned b = __float_as_uint(f);
    unsigned r = (b + 0x7FFFu + ((b >> 16) & 1u)) >> 16;
    return (unsigned short)r;
}
__device__ __forceinline__ float bf2f(unsigned short u){
    return __uint_as_float((unsigned)u << 16);
}

// ---------------- f32 -> bf16 bulk convert (8 elems/thread) ----------------
__global__ void k_cvt(const float* __restrict__ in, unsigned short* __restrict__ out){
    int idx = blockIdx.x*256 + threadIdx.x;
    const float4* s = reinterpret_cast<const float4*>(in + (size_t)idx*8);
    float4 a = s[0], b = s[1];
    unsigned short t[8];
    t[0]=f2bf(a.x); t[1]=f2bf(a.y); t[2]=f2bf(a.z); t[3]=f2bf(a.w);
    t[4]=f2bf(b.x); t[5]=f2bf(b.y); t[6]=f2bf(b.z); t[7]=f2bf(b.w);
    *reinterpret_cast<uint4*>(out + (size_t)idx*8) = *reinterpret_cast<uint4*>(t);
}

// ---------- W [NT][256][256] f32 -> Wt [NT][256(o)][256(i)] bf16 -----------
__global__ __launch_bounds__(256) void k_cvt_w(const float* __restrict__ W,
                                               unsigned short* __restrict__ Wt){
    __shared__ float S[64][65];
    int t = blockIdx.z;
    int i0 = blockIdx.x * 64, o0 = blockIdx.y * 64;
    int th = threadIdx.x;
    int r = th >> 2, c0 = (th & 3) * 16;
    const float* src = W + (size_t)t*65536 + (size_t)(i0 + r)*256 + o0 + c0;
    #pragma unroll
    for (int j = 0; j < 16; j += 4){
        float4 v = *reinterpret_cast<const float4*>(src + j);
        S[r][c0 + j + 0] = v.x; S[r][c0 + j + 1] = v.y;
        S[r][c0 + j + 2] = v.z; S[r][c0 + j + 3] = v.w;
    }
    __syncthreads();
    unsigned short tmp[16];
    #pragma unroll
    for (int j = 0; j < 16; j++) tmp[j] = f2bf(S[c0 + j][r]);
    unsigned short* dst = Wt + (size_t)t*65536 + (size_t)(o0 + r)*256 + i0 + c0;
    *reinterpret_cast<uint4*>(dst)     = *reinterpret_cast<uint4*>(tmp);
    *reinterpret_cast<uint4*>(dst + 8) = *reinterpret_cast<uint4*>(tmp + 8);
}

// rte_vec[m,i] = sum_j emb[m,j]*rte_W[i,j] + rte_b[i]
__global__ void k_rtevec(const float* __restrict__ emb, const float* __restrict__ W,
                         const float* __restrict__ b, float* __restrict__ out){
    __shared__ float se[DIM];
    int m = blockIdx.x, i = threadIdx.x;
    se[i] = emb[m*DIM + i];
    __syncthreads();
    const float* wr = W + i*DIM;
    float acc = 0.f;
    #pragma unroll 8
    for (int j = 0; j < DIM; j += 4){
        float4 w = *reinterpret_cast<const float4*>(wr + j);
        acc += se[j]*w.x + se[j+1]*w.y + se[j+2]*w.z + se[j+3]*w.w;
    }
    out[m*DIM + i] = acc + b[i];
}

// rte_k[t,m,o] = sum_i rvec[m,i]*Wk[t][i,o]  (bf16 out); same for rte_v
__global__ void k_rtekv(const float* __restrict__ rvec, const float* __restrict__ Wk,
                        const float* __restrict__ Wv, unsigned short* __restrict__ rkb,
                        unsigned short* __restrict__ rvb){
    __shared__ float sv[DIM];
    int m = blockIdx.x, t = blockIdx.y, o = threadIdx.x;
    sv[o] = rvec[m*DIM + o];
    __syncthreads();
    const float* wk = Wk + (size_t)t*DIM*DIM;
    const float* wv = Wv + (size_t)t*DIM*DIM;
    float ak = 0.f, av = 0.f;
    #pragma unroll 4
    for (int i = 0; i < DIM; i++){
        float s = sv[i];
        ak += s * wk[i*DIM + o];
        av += s * wv[i*DIM + o];
    }
    rkb[(t*ML+m)*DIM + o] = f2bf(ak);
    rvb[(t*ML+m)*DIM + o] = f2bf(av);
}

// node bucketing (two-level) + dst-degree histogram
__global__ void k_bucket(const int* __restrict__ ntype, const int* __restrict__ edst,
                         int* __restrict__ ncnt, int* __restrict__ nlist,
                         int* __restrict__ deg){
    __shared__ int lc[4];
    __shared__ int lb[4];
    int tid = threadIdx.x;
    if (tid < 4) lc[tid] = 0;
    __syncthreads();
    int idx = blockIdx.x*256 + tid;
    int key = -1, lpos = 0;
    if (idx < NN){
        key = ntype[idx];
        lpos = atomicAdd(&lc[key], 1);
    } else if (idx < NN + NE){
        atomicAdd(&deg[edst[idx - NN]], 1);
    }
    __syncthreads();
    if (tid < 3 && lc[tid] > 0) lb[tid] = atomicAdd(&ncnt[tid], lc[tid]);
    __syncthreads();
    if (idx < NN) nlist[key*NN + lb[key] + lpos] = idx;
}

// exclusive scan of deg[0..NN) -> off[0..NN], single block of 1024
__global__ __launch_bounds__(1024) void k_scan(const int* __restrict__ deg,
                                               int* __restrict__ off){
    __shared__ int wsum[16];
    int t = threadIdx.x;
    int base = t * 32;
    int loc[32];
    int s = 0;
    #pragma unroll
    for (int i = 0; i < 32; i++){
        int idx = base + i;
        int v = (idx < NN) ? deg[idx] : 0;
        loc[i] = s;
        s += v;
    }
    int lane = t & 63, w = t >> 6;
    int sc = s;
    #pragma unroll
    for (int d = 1; d < 64; d <<= 1){
        int o = __shfl_up(sc, d);
        if (lane >= d) sc += o;
    }
    if (lane == 63) wsum[w] = sc;
    __syncthreads();
    if (t == 0){
        int a = 0;
        #pragma unroll
        for (int i = 0; i < 16; i++){ int v = wsum[i]; wsum[i] = a; a += v; }
    }
    __syncthreads();
    int tex = (sc - s) + wsum[w];
    #pragma unroll
    for (int i = 0; i < 32; i++){
        int idx = base + i;
        if (idx <= NN) off[idx] = tex + loc[i];
    }
}

// fill CSR slots: packed {src, ((st*ML+time)<<3)|r}
__global__ void k_scatter(const int* __restrict__ esrc, const int* __restrict__ edst,
                          const int* __restrict__ etype, const int* __restrict__ etime,
                          const int* __restrict__ ntype, const int* __restrict__ off,
                          int* __restrict__ cur, uint2* __restrict__ csr){
    int e = blockIdx.x*256 + threadIdx.x;
    if (e >= NE) return;
    int d = edst[e];
    int p = atomicAdd(&cur[d], 1);
    int src = esrc[e];
    int st = ntype[src];
    unsigned meta = ((unsigned)(st*ML + etime[e]) << 3) | (unsigned)etype[e];
    csr[off[d] + p] = make_uint2((unsigned)src, meta);
}

// -------- MFMA bf16 projection: Y[node,:] = Xb[node,:] @ W_t + bias_t ------
template<int BF16OUT>
__global__ __launch_bounds__(256) void k_projM(const unsigned short* __restrict__ Xb,
        const int* __restrict__ nlist, const int* __restrict__ ncnt,
        const unsigned short* __restrict__ Wt, const float* __restrict__ bias,
        float* __restrict__ Yf, unsigned short* __restrict__ Yb){
    __shared__ unsigned short As[128*40];
    __shared__ unsigned short Bs[128*40];
    int t = blockIdx.z;
    int cnt = ncnt[t];
    int m0 = blockIdx.x * 128;
    if (m0 >= cnt) return;
    int o0 = blockIdx.y * 128;
    int th = threadIdx.x;
    const unsigned short* Wtt = Wt + (size_t)t*65536;

    int srow = th >> 1, shalf = th & 1;
    int arow = m0 + srow;
    int anode = (arow < cnt) ? nlist[t*NN + arow] : nlist[t*NN];
    const unsigned short* agp = Xb + (size_t)anode*256 + shalf*16;
    const unsigned short* bgp = Wtt + (size_t)(o0 + srow)*256 + shalf*16;
    uint4* alp = reinterpret_cast<uint4*>(&As[srow*40 + shalf*16]);
    uint4* blp = reinterpret_cast<uint4*>(&Bs[srow*40 + shalf*16]);

    int l = th & 63, w = th >> 6;
    int wm = w >> 1, wn = w & 1;
    int lrow = l & 15, kc = l >> 4;

    f32x4 acc[4][4];
    #pragma unroll
    for (int i = 0; i < 4; i++)
        #pragma unroll
        for (int j = 0; j < 4; j++) acc[i][j] = (f32x4){0.f,0.f,0.f,0.f};

    for (int k0 = 0; k0 < 256; k0 += 32){
        uint4 ga0 = *reinterpret_cast<const uint4*>(agp + k0);
        uint4 ga1 = *reinterpret_cast<const uint4*>(agp + k0 + 8);
        uint4 gb0 = *reinterpret_cast<const uint4*>(bgp + k0);
        uint4 gb1 = *reinterpret_cast<const uint4*>(bgp + k0 + 8);
        __syncthreads();
        alp[0] = ga0; alp[1] = ga1;
        blp[0] = gb0; blp[1] = gb1;
        __syncthreads();
        short8v a[4], b[4];
        #pragma unroll
        for (int mi = 0; mi < 4; mi++)
            a[mi] = *reinterpret_cast<const short8v*>(&As[(wm*64 + mi*16 + lrow)*40 + kc*8]);
        #pragma unroll
        for (int ni = 0; ni < 4; ni++)
            b[ni] = *reinterpret_cast<const short8v*>(&Bs[(wn*64 + ni*16 + lrow)*40 + kc*8]);
        #pragma unroll
        for (int mi = 0; mi < 4; mi++)
            #pragma unroll
            for (int ni = 0; ni < 4; ni++)
                acc[mi][ni] = __builtin_amdgcn_mfma_f32_16x16x32_bf16(a[mi], b[ni], acc[mi][ni], 0, 0, 0);
    }

    float bv[4];
    #pragma unroll
    for (int ni = 0; ni < 4; ni++)
        bv[ni] = bias[t*256 + o0 + wn*64 + ni*16 + (l & 15)];
    #pragma unroll
    for (int mi = 0; mi < 4; mi++){
        #pragma unroll
        for (int j = 0; j < 4; j++){
            int grow = m0 + wm*64 + mi*16 + (l >> 4)*4 + j;
            if (grow < cnt){
                int node = nlist[t*NN + grow];
                size_t cb = (size_t)node*256 + o0 + wn*64 + (l & 15);
                if (BF16OUT){
                    #pragma unroll
                    for (int ni = 0; ni < 4; ni++)
                        Yb[cb + ni*16] = f2bf(acc[mi][ni][j] + bv[ni]);
                } else {
                    #pragma unroll
                    for (int ni = 0; ni < 4; ni++)
                        Yf[cb + ni*16] = acc[mi][ni][j] + bv[ni];
                }
            }
        }
    }
}

// ---- fused attention v3: 16 dst per 1024-thread block, rel tables in LDS ----
// matrix (r,h) stored bf16 at ushort base (r*8+h)*1032, stride-row 32, 2064B
// per matrix (8B aligned).  lane l: head h=l>>3, sub j=l&7, coords [4l,4l+4).
#define TSTRIDE 1032
__global__ __launch_bounds__(1024) void k_attn3(
        const unsigned short* __restrict__ qb, const unsigned short* __restrict__ kb,
        const unsigned short* __restrict__ vb, const unsigned short* __restrict__ rkb,
        const unsigned short* __restrict__ rvb, const int* __restrict__ off,
        const uint2* __restrict__ csr, const float* __restrict__ rel_att,
        const float* __restrict__ rel_msg, const float* __restrict__ rel_pri,
        unsigned short* __restrict__ ab){
    __shared__ unsigned short tbl[40*TSTRIDE];   // 82,560 B
    __shared__ float slg[16][512];               // 32,768 B
    int tid = threadIdx.x;
    int ws = tid >> 6;
    int wv = (blockIdx.x << 4) + ws;
    int l = tid & 63;
    int h = l >> 3, j = l & 7;
    int c0 = l*4;

    // ---- stage rel_att (f32 global -> bf16 LDS), coalesced ----
    for (int p = tid; p < 20480; p += 1024){
        int r = p >> 12, hh = (p >> 9) & 7, dfp = p & 511;
        float a = rel_att[(size_t)p*2];
        float b = rel_att[(size_t)p*2 + 1];
        unsigned pk = (unsigned)f2bf(a) | ((unsigned)f2bf(b) << 16);
        *reinterpret_cast<unsigned*>(
            reinterpret_cast<char*>(tbl) + (r*8 + hh)*2064 + dfp*4) = pk;
    }
    __syncthreads();

    int eb = off[wv], ee = off[wv + 1];
    int deg = ee - eb;
    int n1 = deg < 64 ? deg : 64;

    int cidx = (deg > 0) ? (eb + (l < deg ? l : deg - 1)) : 0;
    uint2 eml = csr[cidx];

    const float inv = 0.17677669529663687f;  // 1/sqrt(32)
    float pr0 = rel_pri[0*NH + h]*inv, pr1 = rel_pri[1*NH + h]*inv;
    float pr2 = rel_pri[2*NH + h]*inv, pr3 = rel_pri[3*NH + h]*inv;
    float pr4 = rel_pri[4*NH + h]*inv;

    float q4[4];
    {
        ushort4 qq = *reinterpret_cast<const ushort4*>(qb + (size_t)wv*DIM + c0);
        q4[0] = bf2f(qq.x); q4[1] = bf2f(qq.y); q4[2] = bf2f(qq.z); q4[3] = bf2f(qq.w);
    }

    // qt[r][dd] = (M_att[r][h] @ q)[4j+dd]   (8-step lane rotate, LDS reads)
    float qt[NR][4];
    #pragma unroll
    for (int r = 0; r < NR; r++){ qt[r][0]=0.f; qt[r][1]=0.f; qt[r][2]=0.f; qt[r][3]=0.f; }
    #pragma unroll
    for (int s = 0; s < 8; s++){
        int jj = (j + s) & 7;
        int srcl = (l & 0x38) | jj;
        float qs0 = __shfl(q4[0], srcl), qs1 = __shfl(q4[1], srcl);
        float qs2 = __shfl(q4[2], srcl), qs3 = __shfl(q4[3], srcl);
        #pragma unroll
        for (int r = 0; r < NR; r++){
            const unsigned short* Mb = tbl + (r*8 + h)*TSTRIDE;
            #pragma unroll
            for (int dd = 0; dd < 4; dd++){
                ushort4 mr = *reinterpret_cast<const ushort4*>(Mb + (4*j + dd)*32 + 4*jj);
                qt[r][dd] += qs0*bf2f(mr.x) + qs1*bf2f(mr.y) + qs2*bf2f(mr.z) + qs3*bf2f(mr.w);
            }
        }
    }
    __syncthreads();

    // ---- restage rel_msg over the same LDS ----
    for (int p = tid; p < 20480; p += 1024){
        int r = p >> 12, hh = (p >> 9) & 7, dfp = p & 511;
        float a = rel_msg[(size_t)p*2];
        float b = rel_msg[(size_t)p*2 + 1];
        unsigned pk = (unsigned)f2bf(a) | ((unsigned)f2bf(b) << 16);
        *reinterpret_cast<unsigned*>(
            reinterpret_cast<char*>(tbl) + (r*8 + hh)*2064 + dfp*4) = pk;
    }
    __syncthreads();

    float m_run = -1e30f, den = 0.f;

    // ---- loop 1: logits + scalar online max/den; stage lg in LDS ----
    #pragma unroll 2
    for (int e = 0; e < n1; e++){
        int sl = __shfl((int)eml.x, e);
        int mt = __shfl((int)eml.y, e);
        int r  = mt & 7;
        int rr = mt >> 3;
        ushort4 kk = *reinterpret_cast<const ushort4*>(kb + (size_t)sl*DIM + c0);
        ushort4 rk = *reinterpret_cast<const ushort4*>(rkb + (size_t)rr*DIM + c0);
        float k0 = bf2f(kk.x)+bf2f(rk.x), k1 = bf2f(kk.y)+bf2f(rk.y);
        float k2 = bf2f(kk.z)+bf2f(rk.z), k3 = bf2f(kk.w)+bf2f(rk.w);
        float dt, pri;
        switch (r){
            case 0: dt = qt[0][0]*k0+qt[0][1]*k1+qt[0][2]*k2+qt[0][3]*k3; pri = pr0; break;
            case 1: dt = qt[1][0]*k0+qt[1][1]*k1+qt[1][2]*k2+qt[1][3]*k3; pri = pr1; break;
            case 2: dt = qt[2][0]*k0+qt[2][1]*k1+qt[2][2]*k2+qt[2][3]*k3; pri = pr2; break;
            case 3: dt = qt[3][0]*k0+qt[3][1]*k1+qt[3][2]*k2+qt[3][3]*k3; pri = pr3; break;
            default:dt = qt[4][0]*k0+qt[4][1]*k1+qt[4][2]*k2+qt[4][3]*k3; pri = pr4; break;
        }
        dt += __shfl_xor(dt, 1);
        dt += __shfl_xor(dt, 2);
        dt += __shfl_xor(dt, 4);
        float lg = dt * pri;
        if (j == 0) slg[ws][e*8 + h] = lg;
        float mnew = fmaxf(m_run, lg);
        den = den*__expf(m_run - mnew) + __expf(lg - mnew);
        m_run = mnew;
    }
    for (int e = 64; e < deg; e++){
        uint2 em = csr[eb + e];
        int sl = (int)em.x, mt = (int)em.y;
        int r = mt & 7, rr = mt >> 3;
        ushort4 kk = *reinterpret_cast<const ushort4*>(kb + (size_t)sl*DIM + c0);
        ushort4 rk = *reinterpret_cast<const ushort4*>(rkb + (size_t)rr*DIM + c0);
        float k0 = bf2f(kk.x)+bf2f(rk.x), k1 = bf2f(kk.y)+bf2f(rk.y);
        float k2 = bf2f(kk.z)+bf2f(rk.z), k3 = bf2f(kk.w)+bf2f(rk.w);
        float dt, pri;
        switch (r){
            case 0: dt = qt[0][0]*k0+qt[0][1]*k1+qt[0][2]*k2+qt[0][3]*k3; pri = pr0; break;
            case 1: dt = qt[1][0]*k0+qt[1][1]*k1+qt[1][2]*k2+qt[1][3]*k3; pri = pr1; break;
            case 2: dt = qt[2][0]*k0+qt[2][1]*k1+qt[2][2]*k2+qt[2][3]*k3; pri = pr2; break;
            case 3: dt = qt[3][0]*k0+qt[3][1]*k1+qt[3][2]*k2+qt[3][3]*k3; pri = pr3; break;
            default:dt = qt[4][0]*k0+qt[4][1]*k1+qt[4][2]*k2+qt[4][3]*k3; pri = pr4; break;
        }
        dt += __shfl_xor(dt, 1);
        dt += __shfl_xor(dt, 2);
        dt += __shfl_xor(dt, 4);
        float lg = dt * pri;
        float mnew = fmaxf(m_run, lg);
        den = den*__expf(m_run - mnew) + __expf(lg - mnew);
        m_run = mnew;
    }

    float iden = (den > 0.f) ? (1.f / den) : 0.f;
    float acc[NR][4];
    #pragma unroll
    for (int r = 0; r < NR; r++){ acc[r][0]=0.f; acc[r][1]=0.f; acc[r][2]=0.f; acc[r][3]=0.f; }

    // ---- loop 2: att * (v + rte_v), accumulate per relation ----
    #pragma unroll 2
    for (int e = 0; e < n1; e++){
        int sl = __shfl((int)eml.x, e);
        int mt = __shfl((int)eml.y, e);
        int r  = mt & 7;
        int rr = mt >> 3;
        float at = __expf(slg[ws][e*8 + h] - m_run) * iden;
        ushort4 vv = *reinterpret_cast<const ushort4*>(vb + (size_t)sl*DIM + c0);
        ushort4 rv = *reinterpret_cast<const ushort4*>(rvb + (size_t)rr*DIM + c0);
        float v0 = bf2f(vv.x)+bf2f(rv.x), v1 = bf2f(vv.y)+bf2f(rv.y);
        float v2 = bf2f(vv.z)+bf2f(rv.z), v3 = bf2f(vv.w)+bf2f(rv.w);
        switch (r){
            case 0: acc[0][0]+=at*v0; acc[0][1]+=at*v1; acc[0][2]+=at*v2; acc[0][3]+=at*v3; break;
            case 1: acc[1][0]+=at*v0; acc[1][1]+=at*v1; acc[1][2]+=at*v2; acc[1][3]+=at*v3; break;
            case 2: acc[2][0]+=at*v0; acc[2][1]+=at*v1; acc[2][2]+=at*v2; acc[2][3]+=at*v3; break;
            case 3: acc[3][0]+=at*v0; acc[3][1]+=at*v1; acc[3][2]+=at*v2; acc[3][3]+=at*v3; break;
            default:acc[4][0]+=at*v0; acc[4][1]+=at*v1; acc[4][2]+=at*v2; acc[4][3]+=at*v3; break;
        }
    }
    for (int e = 64; e < deg; e++){
        uint2 em = csr[eb + e];
        int sl = (int)em.x, mt = (int)em.y;
        int r = mt & 7, rr = mt >> 3;
        ushort4 kk = *reinterpret_cast<const ushort4*>(kb + (size_t)sl*DIM + c0);
        ushort4 rk = *reinterpret_cast<const ushort4*>(rkb + (size_t)rr*DIM + c0);
        float k0 = bf2f(kk.x)+bf2f(rk.x), k1 = bf2f(kk.y)+bf2f(rk.y);
        float k2 = bf2f(kk.z)+bf2f(rk.z), k3 = bf2f(kk.w)+bf2f(rk.w);
        float dt, pri;
        switch (r){
            case 0: dt = qt[0][0]*k0+qt[0][1]*k1+qt[0][2]*k2+qt[0][3]*k3; pri = pr0; break;
            case 1: dt = qt[1][0]*k0+qt[1][1]*k1+qt[1][2]*k2+qt[1][3]*k3; pri = pr1; break;
            case 2: dt = qt[2][0]*k0+qt[2][1]*k1+qt[2][2]*k2+qt[2][3]*k3; pri = pr2; break;
            case 3: dt = qt[3][0]*k0+qt[3][1]*k1+qt[3][2]*k2+qt[3][3]*k3; pri = pr3; break;
            default:dt = qt[4][0]*k0+qt[4][1]*k1+qt[4][2]*k2+qt[4][3]*k3; pri = pr4; break;
        }
        dt += __shfl_xor(dt, 1);
        dt += __shfl_xor(dt, 2);
        dt += __shfl_xor(dt, 4);
        float at = __expf(dt*pri - m_run) * iden;
        ushort4 vv = *reinterpret_cast<const ushort4*>(vb + (size_t)sl*DIM + c0);
        ushort4 rv = *reinterpret_cast<const ushort4*>(rvb + (size_t)rr*DIM + c0);
        float v0 = bf2f(vv.x)+bf2f(rv.x), v1 = bf2f(vv.y)+bf2f(rv.y);
        float v2 = bf2f(vv.z)+bf2f(rv.z), v3 = bf2f(vv.w)+bf2f(rv.w);
        switch (r){
            case 0: acc[0][0]+=at*v0; acc[0][1]+=at*v1; acc[0][2]+=at*v2; acc[0][3]+=at*v3; break;
            case 1: acc[1][0]+=at*v0; acc[1][1]+=at*v1; acc[1][2]+=at*v2; acc[1][3]+=at*v3; break;
            case 2: acc[2][0]+=at*v0; acc[2][1]+=at*v1; acc[2][2]+=at*v2; acc[2][3]+=at*v3; break;
            case 3: acc[3][0]+=at*v0; acc[3][1]+=at*v1; acc[3][2]+=at*v2; acc[3][3]+=at*v3; break;
            default:acc[4][0]+=at*v0; acc[4][1]+=at*v1; acc[4][2]+=at*v2; acc[4][3]+=at*v3; break;
        }
    }

    // out[f] = sum_r sum_d acc[r][d] * M_msg[r][h][d][f]  (att already /den; LDS)
    float o[4] = {0.f, 0.f, 0.f, 0.f};
    #pragma unroll
    for (int s = 0; s < 8; s++){
        int jj = (j + s) & 7;
        int srcl = (l & 0x38) | jj;
        #pragma unroll
        for (int r = 0; r < NR; r++){
            float a0 = __shfl(acc[r][0], srcl);
            float a1 = __shfl(acc[r][1], srcl);
            float a2 = __shfl(acc[r][2], srcl);
            float a3 = __shfl(acc[r][3], srcl);
            const unsigned short* Mb = tbl + (r*8 + h)*TSTRIDE + 4*j;
            ushort4 m0 = *reinterpret_cast<const ushort4*>(Mb + (4*jj + 0)*32);
            ushort4 m1 = *reinterpret_cast<const ushort4*>(Mb + (4*jj + 1)*32);
            ushort4 m2 = *reinterpret_cast<const ushort4*>(Mb + (4*jj + 2)*32);
            ushort4 m3 = *reinterpret_cast<const ushort4*>(Mb + (4*jj + 3)*32);
            o[0] += a0*bf2f(m0.x) + a1*bf2f(m1.x) + a2*bf2f(m2.x) + a3*bf2f(m3.x);
            o[1] += a0*bf2f(m0.y) + a1*bf2f(m1.y) + a2*bf2f(m2.y) + a3*bf2f(m3.y);
            o[2] += a0*bf2f(m0.z) + a1*bf2f(m1.z) + a2*bf2f(m2.z) + a3*bf2f(m3.z);
            o[3] += a0*bf2f(m0.w) + a1*bf2f(m1.w) + a2*bf2f(m2.w) + a3*bf2f(m3.w);
        }
    }
    ushort4 res;
    res.x = f2bf(o[0]); res.y = f2bf(o[1]);
    res.z = f2bf(o[2]); res.w = f2bf(o[3]);
    *reinterpret_cast<ushort4*>(ab + (size_t)wv*DIM + c0) = res;
}

__global__ __launch_bounds__(256) void k_epi(const float* __restrict__ trans,
        const float* __restrict__ x, const int* __restrict__ ntype,
        const float* __restrict__ skip, const float* __restrict__ g,
        const float* __restrict__ b, float* __restrict__ out){
    __shared__ float r1[4], r2[4];
    int n = blockIdx.x, c = threadIdx.x;
    int t = ntype[n];
    float alpha = 1.f / (1.f + expf(-skip[t]));
    float mixed = trans[(size_t)n*DIM + c]*alpha + x[(size_t)n*DIM + c]*(1.f - alpha);
    float s = mixed, q = mixed*mixed;
    #pragma unroll
    for (int off = 32; off >= 1; off >>= 1){
        s += __shfl_down(s, off);
        q += __shfl_down(q, off);
    }
    int w = c >> 6;
    if ((c & 63) == 0){ r1[w] = s; r2[w] = q; }
    __syncthreads();
    float S  = r1[0]+r1[1]+r1[2]+r1[3];
    float S2 = r2[0]+r2[1]+r2[2]+r2[3];
    float mu = S * (1.f/DIM);
    float var = S2 * (1.f/DIM) - mu*mu;
    out[(size_t)n*DIM + c] = (mixed - mu) * rsqrtf(var + EPSF) * g[t*DIM + c] + b[t*DIM + c];
}

extern "C" void kernel_launch(void* const* d_in, const int* in_sizes, int n_in,
                              void* d_out, int out_size, void* d_ws, size_t ws_size,
                              hipStream_t stream){
    const float* node_inp = (const float*)d_in[0];
    const float* Wk  = (const float*)d_in[1];
    const float* bk  = (const float*)d_in[2];
    const float* Wq  = (const float*)d_in[3];
    const float* bq  = (const float*)d_in[4];
    const float* Wv  = (const float*)d_in[5];
    const float* bv  = (const float*)d_in[6];
    const float* Wa  = (const float*)d_in[7];
    const float* ba  = (const float*)d_in[8];
    const float* ln_g = (const float*)d_in[9];
    const float* ln_b = (const float*)d_in[10];
    const float* rel_pri = (const float*)d_in[11];
    const float* rel_att = (const float*)d_in[12];
    const float* rel_msg = (const float*)d_in[13];
    const float* skip  = (const float*)d_in[14];
    const float* rte_W = (const float*)d_in[15];
    const float* rte_b = (const float*)d_in[16];
    const float* rte_emb = (const float*)d_in[17];
    const int* ntype = (const int*)d_in[18];
    const int* eidx  = (const int*)d_in[19];
    const int* etype = (const int*)d_in[20];
    const int* etime = (const int*)d_in[21];
    const int* esrc = eidx;
    const int* edst = eidx + NE;

    char* base = (char*)d_ws;
    unsigned short* qb  = (unsigned short*)(base);
    unsigned short* kb  = (unsigned short*)(base + 15360000);
    unsigned short* vb  = (unsigned short*)(base + 30720000);
    unsigned short* ab  = (unsigned short*)(base + 46080000);
    unsigned short* rkb = (unsigned short*)(base + 61440000);
    unsigned short* rvb = (unsigned short*)(base + 61808640);
    float* rvec         = (float*)(base + 62177280);
    int* ncnt           = (int*)(base + 62423040);   // memset region start
    int* deg            = (int*)(base + 62423104);
    int* cur            = (int*)(base + 62543104);
    int* off            = (int*)(base + 62663104);
    uint2* csr          = (uint2*)(base + 62783168);
    int* nlist          = (int*)(base + 64383168);
    float* trans        = (float*)kb;                 // overlays kb+vb (dead after k_attn3)
    float* out = (float*)d_out;

    // d_out scratch (dead once final out written): bf16 node_inp + 4 bf16 W^T
    unsigned short* xb  = (unsigned short*)d_out;
    unsigned short* wtb = (unsigned short*)((char*)d_out + 15360000);
    unsigned short* wtq = wtb;
    unsigned short* wtk = wtb + 1*(size_t)NT*DIM*DIM;
    unsigned short* wtv = wtb + 2*(size_t)NT*DIM*DIM;
    unsigned short* wta = wtb + 3*(size_t)NT*DIM*DIM;

    hipMemsetAsync((void*)ncnt, 0, 64 + 120000 + 120000, stream);
    k_cvt<<<NN*DIM/(8*256), 256, 0, stream>>>(node_inp, xb);
    dim3 wgrid(4, 4, NT);
    k_cvt_w<<<wgrid, 256, 0, stream>>>(Wq, wtq);
    k_cvt_w<<<wgrid, 256, 0, stream>>>(Wk, wtk);
    k_cvt_w<<<wgrid, 256, 0, stream>>>(Wv, wtv);
    k_cvt_w<<<wgrid, 256, 0, stream>>>(Wa, wta);
    k_rtevec<<<ML, 256, 0, stream>>>(rte_emb, rte_W, rte_b, rvec);
    k_rtekv<<<dim3(ML, NT), 256, 0, stream>>>(rvec, Wk, Wv, rkb, rvb);
    k_bucket<<<(NN+NE+255)/256, 256, 0, stream>>>(ntype, edst, ncnt, nlist, deg);
    k_scan<<<1, 1024, 0, stream>>>(deg, off);
    k_scatter<<<(NE+255)/256, 256, 0, stream>>>(esrc, edst, etype, etime, ntype, off, cur, csr);

    dim3 pgrid((NN+127)/128, 2, NT);
    k_projM<1><<<pgrid, 256, 0, stream>>>(xb, nlist, ncnt, wtq, bq, nullptr, qb);
    k_projM<1><<<pgrid, 256, 0, stream>>>(xb, nlist, ncnt, wtk, bk, nullptr, kb);
    k_projM<1><<<pgrid, 256, 0, stream>>>(xb, nlist, ncnt, wtv, bv, nullptr, vb);
    k_attn3<<<NN/16, 1024, 0, stream>>>(qb, kb, vb, rkb, rvb, off, csr,
                                        rel_att, rel_msg, rel_pri, ab);
    k_projM<0><<<pgrid, 256, 0, stream>>>(ab, nlist, ncnt, wta, ba, trans, nullptr);
    k_epi<<<NN, 256, 0, stream>>>(trans, node_inp, ntype, skip, ln_g, ln_b, out);
}

// Round 9
// 626.279 us; speedup vs baseline: 13.2761x; 13.2761x over previous
//
#include <hip/hip_runtime.h>
#include <hip/hip_bf16.h>
#include <math.h>

#define NN 30000
#define NE 200000
#define NT 3
#define NR 5
#define NH 8
#define DIM 256
#define ML 240
#define EPSF 1e-5f

typedef __attribute__((ext_vector_type(8))) short short8v;
typedef __attribute__((ext_vector_type(4))) float f32x4;

__device__ __forceinline__ unsigned short f2bf(float f){
    unsigned b = __float_as_uint(f);
    unsigned r = (b + 0x7FFFu + ((b >> 16) & 1u)) >> 16;
    return (unsigned short)r;
}
__device__ __forceinline__ float bf2f(unsigned short u){
    return __uint_as_float((unsigned)u << 16);
}

// ---------------- f32 -> bf16 bulk convert (8 elems/thread) ----------------
__global__ void k_cvt(const float* __restrict__ in, unsigned short* __restrict__ out){
    int idx = blockIdx.x*256 + threadIdx.x;
    const float4* s = reinterpret_cast<const float4*>(in + (size_t)idx*8);
    float4 a = s[0], b = s[1];
    unsigned short t[8];
    t[0]=f2bf(a.x); t[1]=f2bf(a.y); t[2]=f2bf(a.z); t[3]=f2bf(a.w);
    t[4]=f2bf(b.x); t[5]=f2bf(b.y); t[6]=f2bf(b.z); t[7]=f2bf(b.w);
    *reinterpret_cast<uint4*>(out + (size_t)idx*8) = *reinterpret_cast<uint4*>(t);
}

// ---------- W [NT][256][256] f32 -> Wt [NT][256(o)][256(i)] bf16 -----------
__global__ __launch_bounds__(256) void k_cvt_w(const float* __restrict__ W,
                                               unsigned short* __restrict__ Wt){
    __shared__ float S[64][65];
    int t = blockIdx.z;
    int i0 = blockIdx.x * 64, o0 = blockIdx.y * 64;
    int th = threadIdx.x;
    int r = th >> 2, c0 = (th & 3) * 16;
    const float* src = W + (size_t)t*65536 + (size_t)(i0 + r)*256 + o0 + c0;
    #pragma unroll
    for (int j = 0; j < 16; j += 4){
        float4 v = *reinterpret_cast<const float4*>(src + j);
        S[r][c0 + j + 0] = v.x; S[r][c0 + j + 1] = v.y;
        S[r][c0 + j + 2] = v.z; S[r][c0 + j + 3] = v.w;
    }
    __syncthreads();
    unsigned short tmp[16];
    #pragma unroll
    for (int j = 0; j < 16; j++) tmp[j] = f2bf(S[c0 + j][r]);
    unsigned short* dst = Wt + (size_t)t*65536 + (size_t)(o0 + r)*256 + i0 + c0;
    *reinterpret_cast<uint4*>(dst)     = *reinterpret_cast<uint4*>(tmp);
    *reinterpret_cast<uint4*>(dst + 8) = *reinterpret_cast<uint4*>(tmp + 8);
}

// rte_vec[m,i] = sum_j emb[m,j]*rte_W[i,j] + rte_b[i]
__global__ void k_rtevec(const float* __restrict__ emb, const float* __restrict__ W,
                         const float* __restrict__ b, float* __restrict__ out){
    __shared__ float se[DIM];
    int m = blockIdx.x, i = threadIdx.x;
    se[i] = emb[m*DIM + i];
    __syncthreads();
    const float* wr = W + i*DIM;
    float acc = 0.f;
    #pragma unroll 8
    for (int j = 0; j < DIM; j += 4){
        float4 w = *reinterpret_cast<const float4*>(wr + j);
        acc += se[j]*w.x + se[j+1]*w.y + se[j+2]*w.z + se[j+3]*w.w;
    }
    out[m*DIM + i] = acc + b[i];
}

// rte_k[t,m,o] = sum_i rvec[m,i]*Wk[t][i,o]  (bf16 out); same for rte_v
__global__ void k_rtekv(const float* __restrict__ rvec, const float* __restrict__ Wk,
                        const float* __restrict__ Wv, unsigned short* __restrict__ rkb,
                        unsigned short* __restrict__ rvb){
    __shared__ float sv[DIM];
    int m = blockIdx.x, t = blockIdx.y, o = threadIdx.x;
    sv[o] = rvec[m*DIM + o];
    __syncthreads();
    const float* wk = Wk + (size_t)t*DIM*DIM;
    const float* wv = Wv + (size_t)t*DIM*DIM;
    float ak = 0.f, av = 0.f;
    #pragma unroll 4
    for (int i = 0; i < DIM; i++){
        float s = sv[i];
        ak += s * wk[i*DIM + o];
        av += s * wv[i*DIM + o];
    }
    rkb[(t*ML+m)*DIM + o] = f2bf(ak);
    rvb[(t*ML+m)*DIM + o] = f2bf(av);
}

// node bucketing (two-level) + dst-degree histogram
__global__ void k_bucket(const int* __restrict__ ntype, const int* __restrict__ edst,
                         int* __restrict__ ncnt, int* __restrict__ nlist,
                         int* __restrict__ deg){
    __shared__ int lc[4];
    __shared__ int lb[4];
    int tid = threadIdx.x;
    if (tid < 4) lc[tid] = 0;
    __syncthreads();
    int idx = blockIdx.x*256 + tid;
    int key = -1, lpos = 0;
    if (idx < NN){
        key = ntype[idx];
        lpos = atomicAdd(&lc[key], 1);
    } else if (idx < NN + NE){
        atomicAdd(&deg[edst[idx - NN]], 1);
    }
    __syncthreads();
    if (tid < 3 && lc[tid] > 0) lb[tid] = atomicAdd(&ncnt[tid], lc[tid]);
    __syncthreads();
    if (idx < NN) nlist[key*NN + lb[key] + lpos] = idx;
}

// exclusive scan of deg[0..NN) -> off[0..NN], single block of 1024
__global__ __launch_bounds__(1024) void k_scan(const int* __restrict__ deg,
                                               int* __restrict__ off){
    __shared__ int wsum[16];
    int t = threadIdx.x;
    int base = t * 32;
    int loc[32];
    int s = 0;
    #pragma unroll
    for (int i = 0; i < 32; i++){
        int idx = base + i;
        int v = (idx < NN) ? deg[idx] : 0;
        loc[i] = s;
        s += v;
    }
    int lane = t & 63, w = t >> 6;
    int sc = s;
    #pragma unroll
    for (int d = 1; d < 64; d <<= 1){
        int o = __shfl_up(sc, d);
        if (lane >= d) sc += o;
    }
    if (lane == 63) wsum[w] = sc;
    __syncthreads();
    if (t == 0){
        int a = 0;
        #pragma unroll
        for (int i = 0; i < 16; i++){ int v = wsum[i]; wsum[i] = a; a += v; }
    }
    __syncthreads();
    int tex = (sc - s) + wsum[w];
    #pragma unroll
    for (int i = 0; i < 32; i++){
        int idx = base + i;
        if (idx <= NN) off[idx] = tex + loc[i];
    }
}

// fill CSR slots: packed {src, ((st*ML+time)<<3)|r}
__global__ void k_scatter(const int* __restrict__ esrc, const int* __restrict__ edst,
                          const int* __restrict__ etype, const int* __restrict__ etime,
                          const int* __restrict__ ntype, const int* __restrict__ off,
                          int* __restrict__ cur, uint2* __restrict__ csr){
    int e = blockIdx.x*256 + threadIdx.x;
    if (e >= NE) return;
    int d = edst[e];
    int p = atomicAdd(&cur[d], 1);
    int src = esrc[e];
    int st = ntype[src];
    unsigned meta = ((unsigned)(st*ML + etime[e]) << 3) | (unsigned)etype[e];
    csr[off[d] + p] = make_uint2((unsigned)src, meta);
}

// -------- MFMA bf16 projection: Y[node,:] = Xb[node,:] @ W_t + bias_t ------
template<int BF16OUT>
__global__ __launch_bounds__(256) void k_projM(const unsigned short* __restrict__ Xb,
        const int* __restrict__ nlist, const int* __restrict__ ncnt,
        const unsigned short* __restrict__ Wt, const float* __restrict__ bias,
        float* __restrict__ Yf, unsigned short* __restrict__ Yb){
    __shared__ unsigned short As[128*40];
    __shared__ unsigned short Bs[128*40];
    int t = blockIdx.z;
    int cnt = ncnt[t];
    int m0 = blockIdx.x * 128;
    if (m0 >= cnt) return;
    int o0 = blockIdx.y * 128;
    int th = threadIdx.x;
    const unsigned short* Wtt = Wt + (size_t)t*65536;

    int srow = th >> 1, shalf = th & 1;
    int arow = m0 + srow;
    int anode = (arow < cnt) ? nlist[t*NN + arow] : nlist[t*NN];
    const unsigned short* agp = Xb + (size_t)anode*256 + shalf*16;
    const unsigned short* bgp = Wtt + (size_t)(o0 + srow)*256 + shalf*16;
    uint4* alp = reinterpret_cast<uint4*>(&As[srow*40 + shalf*16]);
    uint4* blp = reinterpret_cast<uint4*>(&Bs[srow*40 + shalf*16]);

    int l = th & 63, w = th >> 6;
    int wm = w >> 1, wn = w & 1;
    int lrow = l & 15, kc = l >> 4;

    f32x4 acc[4][4];
    #pragma unroll
    for (int i = 0; i < 4; i++)
        #pragma unroll
        for (int j = 0; j < 4; j++) acc[i][j] = (f32x4){0.f,0.f,0.f,0.f};

    for (int k0 = 0; k0 < 256; k0 += 32){
        uint4 ga0 = *reinterpret_cast<const uint4*>(agp + k0);
        uint4 ga1 = *reinterpret_cast<const uint4*>(agp + k0 + 8);
        uint4 gb0 = *reinterpret_cast<const uint4*>(bgp + k0);
        uint4 gb1 = *reinterpret_cast<const uint4*>(bgp + k0 + 8);
        __syncthreads();
        alp[0] = ga0; alp[1] = ga1;
        blp[0] = gb0; blp[1] = gb1;
        __syncthreads();
        short8v a[4], b[4];
        #pragma unroll
        for (int mi = 0; mi < 4; mi++)
            a[mi] = *reinterpret_cast<const short8v*>(&As[(wm*64 + mi*16 + lrow)*40 + kc*8]);
        #pragma unroll
        for (int ni = 0; ni < 4; ni++)
            b[ni] = *reinterpret_cast<const short8v*>(&Bs[(wn*64 + ni*16 + lrow)*40 + kc*8]);
        #pragma unroll
        for (int mi = 0; mi < 4; mi++)
            #pragma unroll
            for (int ni = 0; ni < 4; ni++)
                acc[mi][ni] = __builtin_amdgcn_mfma_f32_16x16x32_bf16(a[mi], b[ni], acc[mi][ni], 0, 0, 0);
    }

    float bv[4];
    #pragma unroll
    for (int ni = 0; ni < 4; ni++)
        bv[ni] = bias[t*256 + o0 + wn*64 + ni*16 + (l & 15)];
    #pragma unroll
    for (int mi = 0; mi < 4; mi++){
        #pragma unroll
        for (int j = 0; j < 4; j++){
            int grow = m0 + wm*64 + mi*16 + (l >> 4)*4 + j;
            if (grow < cnt){
                int node = nlist[t*NN + grow];
                size_t cb = (size_t)node*256 + o0 + wn*64 + (l & 15);
                if (BF16OUT){
                    #pragma unroll
                    for (int ni = 0; ni < 4; ni++)
                        Yb[cb + ni*16] = f2bf(acc[mi][ni][j] + bv[ni]);
                } else {
                    #pragma unroll
                    for (int ni = 0; ni < 4; ni++)
                        Yf[cb + ni*16] = acc[mi][ni][j] + bv[ni];
                }
            }
        }
    }
}

// ---- fused attention v5: both rel tables in LDS (XOR-swizzled, unpadded),
// 512 thr, flash-style single pass, grid-stride 15 nodes per wave ----
// lane l: head h=l>>3, sub j=l&7, owns coords [4l, 4l+4).
// LDS chunk swizzle: 4-elem chunk c of row d of matrix m stored at chunk
// index c ^ (d&7) ^ (m&7).  Applied at stage AND read.
#define AITER 15
__global__ __launch_bounds__(512, 1) void k_attn5(
        const unsigned short* __restrict__ qb, const unsigned short* __restrict__ kb,
        const unsigned short* __restrict__ vb, const unsigned short* __restrict__ rkb,
        const unsigned short* __restrict__ rvb, const int* __restrict__ off,
        const uint2* __restrict__ csr, const float* __restrict__ rel_att,
        const float* __restrict__ rel_msg, const float* __restrict__ rel_pri,
        unsigned short* __restrict__ ab){
    __shared__ unsigned short tblA[40960];   // 81,920 B
    __shared__ unsigned short tblM[40960];   // 81,920 B  (total = 163,840 = limit)
    int tid = threadIdx.x;
    int ws = tid >> 6;
    int l = tid & 63;
    int h = l >> 3, j = l & 7;
    int c0 = l*4;

    // stage both tables (f32 -> bf16) with chunk XOR swizzle
    unsigned* dA = reinterpret_cast<unsigned*>(tblA);
    unsigned* dM = reinterpret_cast<unsigned*>(tblM);
    for (int q = tid; q < 20480; q += 512){
        int m  = q >> 9;          // matrix index r*8+h
        int w  = q & 511;         // dword within matrix
        int d  = w >> 4;          // row
        int c2 = w & 15;          // dword within row
        int c4 = c2 >> 1, half = c2 & 1;
        int dst = m*512 + d*16 + ((c4 ^ (d & 7) ^ (m & 7)) * 2 + half);
        float2 a = *reinterpret_cast<const float2*>(rel_att + (size_t)q*2);
        float2 b = *reinterpret_cast<const float2*>(rel_msg + (size_t)q*2);
        dA[dst] = (unsigned)f2bf(a.x) | ((unsigned)f2bf(a.y) << 16);
        dM[dst] = (unsigned)f2bf(b.x) | ((unsigned)f2bf(b.y) << 16);
    }
    __syncthreads();

    const float inv = 0.17677669529663687f;  // 1/sqrt(32)
    float pr0 = rel_pri[0*NH + h]*inv, pr1 = rel_pri[1*NH + h]*inv;
    float pr2 = rel_pri[2*NH + h]*inv, pr3 = rel_pri[3*NH + h]*inv;
    float pr4 = rel_pri[4*NH + h]*inv;

    int wbase = ((int)blockIdx.x*8 + ws) * AITER;
    for (int it = 0; it < AITER; it++){
        int wv = wbase + it;
        if (wv >= NN) break;

        int eb = off[wv], ee = off[wv + 1];
        int deg = ee - eb;
        int n1 = deg < 64 ? deg : 64;
        int cidx = (deg > 0) ? (eb + (l < deg ? l : deg - 1)) : 0;
        uint2 eml = csr[cidx];

        float q4[4];
        {
            ushort4 qq = *reinterpret_cast<const ushort4*>(qb + (size_t)wv*DIM + c0);
            q4[0] = bf2f(qq.x); q4[1] = bf2f(qq.y); q4[2] = bf2f(qq.z); q4[3] = bf2f(qq.w);
        }

        // qt[r][dd] = sum_f M_att[r][h][4j+dd][f] * q[f]
        float qt[NR][4];
        #pragma unroll
        for (int r = 0; r < NR; r++){ qt[r][0]=0.f; qt[r][1]=0.f; qt[r][2]=0.f; qt[r][3]=0.f; }
        #pragma unroll
        for (int s = 0; s < 8; s++){
            int cc = (j + s) & 7;
            int srcl = (l & 0x38) | cc;
            float qs0 = __shfl(q4[0], srcl), qs1 = __shfl(q4[1], srcl);
            float qs2 = __shfl(q4[2], srcl), qs3 = __shfl(q4[3], srcl);
            #pragma unroll
            for (int r = 0; r < NR; r++){
                const unsigned short* Mb = tblA + (r*8 + h)*1024;
                #pragma unroll
                for (int dd = 0; dd < 4; dd++){
                    int d = 4*j + dd;
                    ushort4 mr = *reinterpret_cast<const ushort4*>(
                        Mb + d*32 + ((cc ^ (d & 7) ^ h) * 4));
                    qt[r][dd] += qs0*bf2f(mr.x) + qs1*bf2f(mr.y) + qs2*bf2f(mr.z) + qs3*bf2f(mr.w);
                }
            }
        }

        float m_run = -1e30f, den = 0.f;
        float acc[NR][4];
        #pragma unroll
        for (int r = 0; r < NR; r++){ acc[r][0]=0.f; acc[r][1]=0.f; acc[r][2]=0.f; acc[r][3]=0.f; }

        // fused single pass: logit + online softmax + weighted V accumulate
        for (int e = 0; e < n1; e++){
            int sl = __shfl((int)eml.x, e);
            int mt = __shfl((int)eml.y, e);
            int r  = mt & 7;
            int rr = mt >> 3;
            ushort4 kk = *reinterpret_cast<const ushort4*>(kb + (size_t)sl*DIM + c0);
            ushort4 rk = *reinterpret_cast<const ushort4*>(rkb + (size_t)rr*DIM + c0);
            ushort4 vv = *reinterpret_cast<const ushort4*>(vb + (size_t)sl*DIM + c0);
            ushort4 rv = *reinterpret_cast<const ushort4*>(rvb + (size_t)rr*DIM + c0);
            float k0 = bf2f(kk.x)+bf2f(rk.x), k1 = bf2f(kk.y)+bf2f(rk.y);
            float k2 = bf2f(kk.z)+bf2f(rk.z), k3 = bf2f(kk.w)+bf2f(rk.w);
            float dt, pri;
            switch (r){
                case 0: dt = qt[0][0]*k0+qt[0][1]*k1+qt[0][2]*k2+qt[0][3]*k3; pri = pr0; break;
                case 1: dt = qt[1][0]*k0+qt[1][1]*k1+qt[1][2]*k2+qt[1][3]*k3; pri = pr1; break;
                case 2: dt = qt[2][0]*k0+qt[2][1]*k1+qt[2][2]*k2+qt[2][3]*k3; pri = pr2; break;
                case 3: dt = qt[3][0]*k0+qt[3][1]*k1+qt[3][2]*k2+qt[3][3]*k3; pri = pr3; break;
                default:dt = qt[4][0]*k0+qt[4][1]*k1+qt[4][2]*k2+qt[4][3]*k3; pri = pr4; break;
            }
            dt += __shfl_xor(dt, 1);
            dt += __shfl_xor(dt, 2);
            dt += __shfl_xor(dt, 4);
            float lg = dt * pri;
            float mnew = fmaxf(m_run, lg);
            float fac = __expf(m_run - mnew);
            float ex  = __expf(lg - mnew);
            den = den*fac + ex;
            m_run = mnew;
            float v0 = bf2f(vv.x)+bf2f(rv.x), v1 = bf2f(vv.y)+bf2f(rv.y);
            float v2 = bf2f(vv.z)+bf2f(rv.z), v3 = bf2f(vv.w)+bf2f(rv.w);
            #pragma unroll
            for (int r2 = 0; r2 < NR; r2++){
                acc[r2][0]*=fac; acc[r2][1]*=fac; acc[r2][2]*=fac; acc[r2][3]*=fac;
            }
            switch (r){
                case 0: acc[0][0]+=ex*v0; acc[0][1]+=ex*v1; acc[0][2]+=ex*v2; acc[0][3]+=ex*v3; break;
                case 1: acc[1][0]+=ex*v0; acc[1][1]+=ex*v1; acc[1][2]+=ex*v2; acc[1][3]+=ex*v3; break;
                case 2: acc[2][0]+=ex*v0; acc[2][1]+=ex*v1; acc[2][2]+=ex*v2; acc[2][3]+=ex*v3; break;
                case 3: acc[3][0]+=ex*v0; acc[3][1]+=ex*v1; acc[3][2]+=ex*v2; acc[3][3]+=ex*v3; break;
                default:acc[4][0]+=ex*v0; acc[4][1]+=ex*v1; acc[4][2]+=ex*v2; acc[4][3]+=ex*v3; break;
            }
        }
        // tail for deg > 64 (rare)
        for (int e = 64; e < deg; e++){
            uint2 em = csr[eb + e];
            int sl = (int)em.x, mt = (int)em.y;
            int r = mt & 7, rr = mt >> 3;
            ushort4 kk = *reinterpret_cast<const ushort4*>(kb + (size_t)sl*DIM + c0);
            ushort4 rk = *reinterpret_cast<const ushort4*>(rkb + (size_t)rr*DIM + c0);
            ushort4 vv = *reinterpret_cast<const ushort4*>(vb + (size_t)sl*DIM + c0);
            ushort4 rv = *reinterpret_cast<const ushort4*>(rvb + (size_t)rr*DIM + c0);
            float k0 = bf2f(kk.x)+bf2f(rk.x), k1 = bf2f(kk.y)+bf2f(rk.y);
            float k2 = bf2f(kk.z)+bf2f(rk.z), k3 = bf2f(kk.w)+bf2f(rk.w);
            float dt, pri;
            switch (r){
                case 0: dt = qt[0][0]*k0+qt[0][1]*k1+qt[0][2]*k2+qt[0][3]*k3; pri = pr0; break;
                case 1: dt = qt[1][0]*k0+qt[1][1]*k1+qt[1][2]*k2+qt[1][3]*k3; pri = pr1; break;
                case 2: dt = qt[2][0]*k0+qt[2][1]*k1+qt[2][2]*k2+qt[2][3]*k3; pri = pr2; break;
                case 3: dt = qt[3][0]*k0+qt[3][1]*k1+qt[3][2]*k2+qt[3][3]*k3; pri = pr3; break;
                default:dt = qt[4][0]*k0+qt[4][1]*k1+qt[4][2]*k2+qt[4][3]*k3; pri = pr4; break;
            }
            dt += __shfl_xor(dt, 1);
            dt += __shfl_xor(dt, 2);
            dt += __shfl_xor(dt, 4);
            float lg = dt * pri;
            float mnew = fmaxf(m_run, lg);
            float fac = __expf(m_run - mnew);
            float ex  = __expf(lg - mnew);
            den = den*fac + ex;
            m_run = mnew;
            float v0 = bf2f(vv.x)+bf2f(rv.x), v1 = bf2f(vv.y)+bf2f(rv.y);
            float v2 = bf2f(vv.z)+bf2f(rv.z), v3 = bf2f(vv.w)+bf2f(rv.w);
            #pragma unroll
            for (int r2 = 0; r2 < NR; r2++){
                acc[r2][0]*=fac; acc[r2][1]*=fac; acc[r2][2]*=fac; acc[r2][3]*=fac;
            }
            switch (r){
                case 0: acc[0][0]+=ex*v0; acc[0][1]+=ex*v1; acc[0][2]+=ex*v2; acc[0][3]+=ex*v3; break;
                case 1: acc[1][0]+=ex*v0; acc[1][1]+=ex*v1; acc[1][2]+=ex*v2; acc[1][3]+=ex*v3; break;
                case 2: acc[2][0]+=ex*v0; acc[2][1]+=ex*v1; acc[2][2]+=ex*v2; acc[2][3]+=ex*v3; break;
                case 3: acc[3][0]+=ex*v0; acc[3][1]+=ex*v1; acc[3][2]+=ex*v2; acc[3][3]+=ex*v3; break;
                default:acc[4][0]+=ex*v0; acc[4][1]+=ex*v1; acc[4][2]+=ex*v2; acc[4][3]+=ex*v3; break;
            }
        }

        float iden = (den > 0.f) ? (1.f / den) : 0.f;

        // out[f] = (sum_r sum_d acc[r][d] * M_msg[r][h][d][f]) / den
        float o[4] = {0.f, 0.f, 0.f, 0.f};
        #pragma unroll
        for (int s = 0; s < 8; s++){
            int jj = (j + s) & 7;
            int srcl = (l & 0x38) | jj;
            #pragma unroll
            for (int r = 0; r < NR; r++){
                float a0 = __shfl(acc[r][0], srcl);
                float a1 = __shfl(acc[r][1], srcl);
                float a2 = __shfl(acc[r][2], srcl);
                float a3 = __shfl(acc[r][3], srcl);
                const unsigned short* Mb = tblM + (r*8 + h)*1024;
                int d0 = 4*jj;
                ushort4 m0 = *reinterpret_cast<const ushort4*>(
                    Mb + (d0+0)*32 + ((j ^ ((d0+0) & 7) ^ h) * 4));
                ushort4 m1 = *reinterpret_cast<const ushort4*>(
                    Mb + (d0+1)*32 + ((j ^ ((d0+1) & 7) ^ h) * 4));
                ushort4 m2 = *reinterpret_cast<const ushort4*>(
                    Mb + (d0+2)*32 + ((j ^ ((d0+2) & 7) ^ h) * 4));
                ushort4 m3 = *reinterpret_cast<const ushort4*>(
                    Mb + (d0+3)*32 + ((j ^ ((d0+3) & 7) ^ h) * 4));
                o[0] += a0*bf2f(m0.x) + a1*bf2f(m1.x) + a2*bf2f(m2.x) + a3*bf2f(m3.x);
                o[1] += a0*bf2f(m0.y) + a1*bf2f(m1.y) + a2*bf2f(m2.y) + a3*bf2f(m3.y);
                o[2] += a0*bf2f(m0.z) + a1*bf2f(m1.z) + a2*bf2f(m2.z) + a3*bf2f(m3.z);
                o[3] += a0*bf2f(m0.w) + a1*bf2f(m1.w) + a2*bf2f(m2.w) + a3*bf2f(m3.w);
            }
        }
        ushort4 res;
        res.x = f2bf(o[0]*iden); res.y = f2bf(o[1]*iden);
        res.z = f2bf(o[2]*iden); res.w = f2bf(o[3]*iden);
        *reinterpret_cast<ushort4*>(ab + (size_t)wv*DIM + c0) = res;
    }
}

__global__ __launch_bounds__(256) void k_epi(const float* __restrict__ trans,
        const float* __restrict__ x, const int* __restrict__ ntype,
        const float* __restrict__ skip, const float* __restrict__ g,
        const float* __restrict__ b, float* __restrict__ out){
    __shared__ float r1[4], r2[4];
    int n = blockIdx.x, c = threadIdx.x;
    int t = ntype[n];
    float alpha = 1.f / (1.f + expf(-skip[t]));
    float mixed = trans[(size_t)n*DIM + c]*alpha + x[(size_t)n*DIM + c]*(1.f - alpha);
    float s = mixed, q = mixed*mixed;
    #pragma unroll
    for (int off = 32; off >= 1; off >>= 1){
        s += __shfl_down(s, off);
        q += __shfl_down(q, off);
    }
    int w = c >> 6;
    if ((c & 63) == 0){ r1[w] = s; r2[w] = q; }
    __syncthreads();
    float S  = r1[0]+r1[1]+r1[2]+r1[3];
    float S2 = r2[0]+r2[1]+r2[2]+r2[3];
    float mu = S * (1.f/DIM);
    float var = S2 * (1.f/DIM) - mu*mu;
    out[(size_t)n*DIM + c] = (mixed - mu) * rsqrtf(var + EPSF) * g[t*DIM + c] + b[t*DIM + c];
}

extern "C" void kernel_launch(void* const* d_in, const int* in_sizes, int n_in,
                              void* d_out, int out_size, void* d_ws, size_t ws_size,
                              hipStream_t stream){
    const float* node_inp = (const float*)d_in[0];
    const float* Wk  = (const float*)d_in[1];
    const float* bk  = (const float*)d_in[2];
    const float* Wq  = (const float*)d_in[3];
    const float* bq  = (const float*)d_in[4];
    const float* Wv  = (const float*)d_in[5];
    const float* bv  = (const float*)d_in[6];
    const float* Wa  = (const float*)d_in[7];
    const float* ba  = (const float*)d_in[8];
    const float* ln_g = (const float*)d_in[9];
    const float* ln_b = (const float*)d_in[10];
    const float* rel_pri = (const float*)d_in[11];
    const float* rel_att = (const float*)d_in[12];
    const float* rel_msg = (const float*)d_in[13];
    const float* skip  = (const float*)d_in[14];
    const float* rte_W = (const float*)d_in[15];
    const float* rte_b = (const float*)d_in[16];
    const float* rte_emb = (const float*)d_in[17];
    const int* ntype = (const int*)d_in[18];
    const int* eidx  = (const int*)d_in[19];
    const int* etype = (const int*)d_in[20];
    const int* etime = (const int*)d_in[21];
    const int* esrc = eidx;
    const int* edst = eidx + NE;

    char* base = (char*)d_ws;
    unsigned short* qb  = (unsigned short*)(base);
    unsigned short* kb  = (unsigned short*)(base + 15360000);
    unsigned short* vb  = (unsigned short*)(base + 30720000);
    unsigned short* ab  = (unsigned short*)(base + 46080000);
    unsigned short* rkb = (unsigned short*)(base + 61440000);
    unsigned short* rvb = (unsigned short*)(base + 61808640);
    float* rvec         = (float*)(base + 62177280);
    int* ncnt           = (int*)(base + 62423040);   // memset region start
    int* deg            = (int*)(base + 62423104);
    int* cur            = (int*)(base + 62543104);
    int* off            = (int*)(base + 62663104);
    uint2* csr          = (uint2*)(base + 62783168);
    int* nlist          = (int*)(base + 64383168);
    float* trans        = (float*)kb;                 // overlays kb+vb (dead after k_attn5)
    float* out = (float*)d_out;

    // d_out scratch (dead once final out written): bf16 node_inp + 4 bf16 W^T
    unsigned short* xb  = (unsigned short*)d_out;
    unsigned short* wtb = (unsigned short*)((char*)d_out + 15360000);
    unsigned short* wtq = wtb;
    unsigned short* wtk = wtb + 1*(size_t)NT*DIM*DIM;
    unsigned short* wtv = wtb + 2*(size_t)NT*DIM*DIM;
    unsigned short* wta = wtb + 3*(size_t)NT*DIM*DIM;

    (void)hipMemsetAsync((void*)ncnt, 0, 64 + 120000 + 120000, stream);
    k_cvt<<<NN*DIM/(8*256), 256, 0, stream>>>(node_inp, xb);
    dim3 wgrid(4, 4, NT);
    k_cvt_w<<<wgrid, 256, 0, stream>>>(Wq, wtq);
    k_cvt_w<<<wgrid, 256, 0, stream>>>(Wk, wtk);
    k_cvt_w<<<wgrid, 256, 0, stream>>>(Wv, wtv);
    k_cvt_w<<<wgrid, 256, 0, stream>>>(Wa, wta);
    k_rtevec<<<ML, 256, 0, stream>>>(rte_emb, rte_W, rte_b, rvec);
    k_rtekv<<<dim3(ML, NT), 256, 0, stream>>>(rvec, Wk, Wv, rkb, rvb);
    k_bucket<<<(NN+NE+255)/256, 256, 0, stream>>>(ntype, edst, ncnt, nlist, deg);
    k_scan<<<1, 1024, 0, stream>>>(deg, off);
    k_scatter<<<(NE+255)/256, 256, 0, stream>>>(esrc, edst, etype, etime, ntype, off, cur, csr);

    dim3 pgrid((NN+127)/128, 2, NT);
    k_projM<1><<<pgrid, 256, 0, stream>>>(xb, nlist, ncnt, wtq, bq, nullptr, qb);
    k_projM<1><<<pgrid, 256, 0, stream>>>(xb, nlist, ncnt, wtk, bk, nullptr, kb);
    k_projM<1><<<pgrid, 256, 0, stream>>>(xb, nlist, ncnt, wtv, bv, nullptr, vb);
    // 250 blocks x 8 waves x AITER(15) = 30000 dst nodes
    k_attn5<<<250, 512, 0, stream>>>(qb, kb, vb, rkb, rvb, off, csr,
                                     rel_att, rel_msg, rel_pri, ab);
    k_projM<0><<<pgrid, 256, 0, stream>>>(ab, nlist, ncnt, wta, ba, trans, nullptr);
    k_epi<<<NN, 256, 0, stream>>>(trans, node_inp, ntype, skip, ln_g, ln_b, out);
}